// Round 10
// baseline (475.023 us; speedup 1.0000x reference)
//
#include <hip/hip_runtime.h>

typedef unsigned short u16;
typedef unsigned int   u32;
typedef __bf16 bf16x8 __attribute__((ext_vector_type(8)));
typedef float  f32x4  __attribute__((ext_vector_type(4)));
typedef float  f32x16 __attribute__((ext_vector_type(16)));

__device__ __forceinline__ u16 f2bf(float f){
  u32 u = __float_as_uint(f);
  u32 r = (u + 0x7FFFu + ((u >> 16) & 1u)) >> 16;   // RNE
  return (u16)r;
}

// Inline-asm load (survives hipcc's load-sinking). "=&v": dest must not
// alias the address pair (delayed write).
#define GLD(dst, p, OFF) \
  asm volatile("global_load_dwordx4 %0, %1, off offset:" OFF \
               : "=&v"(dst) : "v"(p))
#define WAITV(N) do { \
    asm volatile("s_waitcnt vmcnt(" N ")"); \
    __builtin_amdgcn_sched_barrier(0); \
  } while (0)

// ===========================================================================
// TILED OPERAND LAYOUT (validated R8: 735->397us):
// tile = 32 rows x 16 k = 1KB; elem (row,k) -> tile (row>>5, k>>4),
// lane = (row&31)|(((k>>3)&1)<<5), byte = tile*1024 + lane*16 + (k&7)*2.
// Consumer load = ONE contiguous 1KB block, fully coalesced.
//
// R9 post-mortem: halving B L2 traffic + per-CU bytes was NULL -> gemms are
// not L2-BW- or L1-byte-bound. R10 tests the latency hypothesis: 32 waves/CU
// (2x TLP) via CT=1 (<=64 VGPR) 512-thread blocks, 4 blocks/CU.
// ===========================================================================

// ---------------------------------------------------------------------------
// Pass 1: row sums + f32->bf16 + transpose to tiled layout via LDS.
// ---------------------------------------------------------------------------
__global__ __launch_bounds__(1024) void rowsum_tileA(
    const float* __restrict__ A, u16* __restrict__ Ab, float* __restrict__ ds){
  __shared__ u16 lt[8192];               // 16 tiles x 512 u16 = 16 KB
  const int t = threadIdx.x;
  const int r = t >> 5, q = t & 31;      // row 0..31, 32 threads/row
  const int rg = blockIdx.x;
  const float* ar = A + ((size_t)rg * 32 + r) * 8192;
  float s = 0.f;
  for (int ch = 0; ch < 32; ++ch){
    #pragma unroll
    for (int j = 0; j < 2; ++j){
      const int c4 = ch * 64 + j * 32 + q;           // float4 col index
      float4 v = ((const float4*)ar)[c4];
      s += (v.x + v.y) + (v.z + v.w);
      const int cl = (j * 32 + q) * 4;               // local col 0..255
      const int idx = (cl >> 4) * 512 + ((r | (((cl >> 3) & 1) << 5)) * 8) + (cl & 7);
      ushort4 o;
      o.x = f2bf(v.x); o.y = f2bf(v.y); o.z = f2bf(v.z); o.w = f2bf(v.w);
      *(ushort4*)(lt + idx) = o;
    }
    __syncthreads();
    uint4* dst = (uint4*)(Ab + ((size_t)rg * 512 + ch * 16) * 512);
    dst[t] = ((const uint4*)lt)[t];                  // linear 16KB, coalesced
    __syncthreads();
  }
  #pragma unroll
  for (int m = 16; m > 0; m >>= 1) s += __shfl_xor(s, m, 64);
  if (q == 0) ds[rg * 32 + r] = rsqrtf(s);
}

// ---------------------------------------------------------------------------
// Small feature GEMM: Vt tiles = bf16( ds[i] * sum_k in[i][k] * W[k][o] )
// Output in tiled layout.
// ---------------------------------------------------------------------------
template<int K, int F, bool INBF16>
__global__ __launch_bounds__(256) void small_gemm(
    const void* __restrict__ inp, const float* __restrict__ W,
    const float* __restrict__ ds, u16* __restrict__ Vt){
  constexpr int G   = 256 / F;     // 1 (F=256) or 2 (F=128)
  constexpr int RPB = 16 * G;      // rows per block
  __shared__ float xs[RPB * K];
  const int t  = threadIdx.x;
  const int r0 = blockIdx.x * RPB;
  if constexpr (INBF16){
    const u16* ip = (const u16*)inp + (size_t)r0 * K;
    constexpr int IT = (RPB * K) / (256 * 8);
    #pragma unroll
    for (int j = 0; j < IT; ++j){
      int c = j * 256 + t;
      uint4 v = ((const uint4*)ip)[c];
      float* xp = xs + c * 8;
      xp[0] = __uint_as_float((v.x & 0xFFFFu) << 16);
      xp[1] = __uint_as_float(v.x & 0xFFFF0000u);
      xp[2] = __uint_as_float((v.y & 0xFFFFu) << 16);
      xp[3] = __uint_as_float(v.y & 0xFFFF0000u);
      xp[4] = __uint_as_float((v.z & 0xFFFFu) << 16);
      xp[5] = __uint_as_float(v.z & 0xFFFF0000u);
      xp[6] = __uint_as_float((v.w & 0xFFFFu) << 16);
      xp[7] = __uint_as_float(v.w & 0xFFFF0000u);
    }
  } else {
    const float* ip = (const float*)inp + (size_t)r0 * K;
    constexpr int IT = (RPB * K) / (256 * 4);
    #pragma unroll
    for (int j = 0; j < IT; ++j){
      int c = j * 256 + t;
      ((float4*)xs)[c] = ((const float4*)ip)[c];
    }
  }
  __syncthreads();
  const int o = t % F, g = t / F;
  float acc[16];
  #pragma unroll
  for (int r = 0; r < 16; ++r) acc[r] = 0.f;
  const float* xr = xs + g * 16 * K;
  for (int k = 0; k < K; k += 4){
    float w0 = W[(k+0)*F + o];
    float w1 = W[(k+1)*F + o];
    float w2 = W[(k+2)*F + o];
    float w3 = W[(k+3)*F + o];
    #pragma unroll
    for (int r = 0; r < 16; ++r){
      float4 xv = *(const float4*)(xr + r*K + k);
      acc[r] += xv.x*w0 + xv.y*w1 + xv.z*w2 + xv.w*w3;
    }
  }
  const int rb = r0 + g * 16;              // 16-aligned -> one k-tile
  union { u16 u[16]; uint4 v[2]; } pk;
  #pragma unroll
  for (int r = 0; r < 16; ++r) pk.u[r] = f2bf(acc[r] * ds[rb + r]);
  const size_t tile = ((size_t)(o >> 5) * 512 + (rb >> 4)) * 512;
  uint4* dst = (uint4*)(Vt + tile + (size_t)(o & 31) * 8);
  dst[0]  = pk.v[0];
  dst[32] = pk.v[1];
}

// ---------------------------------------------------------------------------
// Big GEMM, max-TLP variant: 512 thr (8 waves = 4 ks x 2 cg), CT=1 per wave
// (32x32 tile), <=64 VGPR -> 4 blocks/CU = 32 waves/CU (2x R8's TLP).
// Grid = rowg * CG, colg is the FAST index so the CG blocks sharing A rows
// run concurrently (A re-reads are L2/L3 hits).
// Asm pipeline: depth-4, counted vmcnt(6), tiled 1KB loads (R8-proven).
// ---------------------------------------------------------------------------
template<int F, bool RELU, bool OUTF32>
__global__ __launch_bounds__(512, 8) void gemm_tlp(
    const u16* __restrict__ Ab, const u16* __restrict__ Vt,
    const float* __restrict__ ds, u16* __restrict__ Hout, float* __restrict__ Fout){
  constexpr int CG = F / 64;            // col-groups: 4 (F=256), 2 (F=128)
  __shared__ float red[2][32][64];      // 16 KB

  const int t = threadIdx.x, wave = t >> 6, lane = t & 63;
  const int ks = wave >> 1;             // K-split 0..3
  const int cg = wave & 1;              // col half within block
  const int colg = blockIdx.x % CG;     // fast index
  const int rowg = blockIdx.x / CG;
  const int row0 = rowg * 32;
  const int ctile = colg * 2 + cg;      // 32-col tile index

  // tiled pointers: tile stride 512 elems (1KB); ks slice = 128 k-tiles
  const u16* pa = Ab + ((size_t)rowg  * 512 + ks * 128) * 512 + lane * 8;
  const u16* pb = Vt + ((size_t)ctile * 512 + ks * 128) * 512 + lane * 8;

  f32x16 acc0;
  #pragma unroll
  for (int i = 0; i < 16; ++i) acc0[i] = 0.f;

  bf16x8 aQ[4], b0Q[4];
  GLD(aQ[0],pa,"0");    GLD(b0Q[0],pb,"0");
  GLD(aQ[1],pa,"1024"); GLD(b0Q[1],pb,"1024");
  GLD(aQ[2],pa,"2048"); GLD(b0Q[2],pb,"2048");
  GLD(aQ[3],pa,"3072"); GLD(b0Q[3],pb,"3072");
  pa += 2048; pb += 2048;
  #define STEP1(U, OFF) \
    WAITV("6"); \
    acc0 = __builtin_amdgcn_mfma_f32_32x32x16_bf16(aQ[U], b0Q[U], acc0, 0, 0, 0); \
    GLD(aQ[U],pa,OFF); GLD(b0Q[U],pb,OFF)
  for (int it = 0; it < 31; ++it){
    STEP1(0, "0");
    STEP1(1, "1024");
    STEP1(2, "2048");
    STEP1(3, "3072");
    pa += 2048; pb += 2048;
  }
  #undef STEP1
  WAITV("6");
  acc0 = __builtin_amdgcn_mfma_f32_32x32x16_bf16(aQ[0], b0Q[0], acc0, 0, 0, 0);
  WAITV("4");
  acc0 = __builtin_amdgcn_mfma_f32_32x32x16_bf16(aQ[1], b0Q[1], acc0, 0, 0, 0);
  WAITV("2");
  acc0 = __builtin_amdgcn_mfma_f32_32x32x16_bf16(aQ[2], b0Q[2], acc0, 0, 0, 0);
  WAITV("0");
  acc0 = __builtin_amdgcn_mfma_f32_32x32x16_bf16(aQ[3], b0Q[3], acc0, 0, 0, 0);

  // ---- K-split tree reduction: ((ks0+ks2)+(ks1+ks3)), 3 barriers total ----
  // C/D layout (m74/m101): col = lane&31, row = (r&3) + 8*(r>>2) + 4*(lane>>5)
  const int rhi = (lane >> 5) << 2;
  const int cl  = lane & 31;
  const int colb = cg * 32;
  if (ks >= 2){
    #pragma unroll
    for (int r = 0; r < 16; ++r)
      red[ks - 2][(r & 3) + ((r >> 2) << 3) + rhi][colb + cl] = acc0[r];
  }
  __syncthreads();
  if (ks < 2){
    #pragma unroll
    for (int r = 0; r < 16; ++r)
      acc0[r] += red[ks][(r & 3) + ((r >> 2) << 3) + rhi][colb + cl];
  }
  __syncthreads();
  if (ks == 1){
    #pragma unroll
    for (int r = 0; r < 16; ++r)
      red[0][(r & 3) + ((r >> 2) << 3) + rhi][colb + cl] = acc0[r];
  }
  __syncthreads();
  if (ks == 0){
    #pragma unroll
    for (int r = 0; r < 16; ++r){
      const int rl = (r & 3) + ((r >> 2) << 3) + rhi;
      float v = acc0[r] + red[0][rl][colb + cl];
      const int row = row0 + rl;
      const int col = colg * 64 + colb + cl;
      v *= ds[row];
      if (RELU) v = fmaxf(v, 0.f);
      if (OUTF32) Fout[(size_t)row * F + col] = v;
      else        Hout[(size_t)row * F + col] = f2bf(v);
    }
  }
}

// ---------------------------------------------------------------------------
// Attention scores: sc[i] = tanh(Z[i,:] @ Wl^T + bl) @ q + b
// ---------------------------------------------------------------------------
__device__ __forceinline__ float tanh_fast(float x){
  x = fminf(fmaxf(x, -15.f), 15.f);
  float e = __expf(2.f * x);
  return (e - 1.f) / (e + 1.f);
}

__global__ __launch_bounds__(256) void attn_scores(
    const float* __restrict__ Z, const float* __restrict__ Wl,
    const float* __restrict__ bl, const float* __restrict__ q,
    const float* __restrict__ bsc, float* __restrict__ sc){
  __shared__ float wl[128 * 128];          // 64 KiB exactly, swizzled
  const int t = threadIdx.x, lane = t & 63, wave = t >> 6;
  for (int j = 0; j < 64; ++j){
    int idx = j * 256 + t;
    int o = idx >> 7, k = idx & 127;
    int c = k >> 2, e = k & 3;
    wl[o * 128 + (((c ^ (o & 31)) << 2) | e)] = Wl[idx];
  }
  __syncthreads();
  const float bl0 = bl[lane], bl1 = bl[lane + 64];
  const float q0  = q[lane],  q1  = q[lane + 64];
  const float bb  = bsc[0];
  const int r0 = blockIdx.x * 16;
  for (int rr = 0; rr < 4; ++rr){
    int r = r0 + wave * 4 + rr;
    float d0 = 0.f, d1 = 0.f;
    #pragma unroll
    for (int c = 0; c < 32; ++c){
      float4 zv = *(const float4*)(Z + (size_t)r * 128 + c * 4);
      float4 w0 = *(const float4*)&wl[ lane      * 128 + ((c ^ (lane & 31)) << 2)];
      float4 w1 = *(const float4*)&wl[(lane + 64)* 128 + ((c ^ (lane & 31)) << 2)];
      d0 += zv.x*w0.x + zv.y*w0.y + zv.z*w0.z + zv.w*w0.w;
      d1 += zv.x*w1.x + zv.y*w1.y + zv.z*w1.z + zv.w*w1.w;
    }
    float s = tanh_fast(d0 + bl0) * q0 + tanh_fast(d1 + bl1) * q1;
    #pragma unroll
    for (int off = 32; off > 0; off >>= 1) s += __shfl_down(s, off, 64);
    if (lane == 0) sc[r] = s + bb;
  }
}

__global__ __launch_bounds__(1024) void softmax_red(
    const float* __restrict__ sc, float* __restrict__ sred){
  const int t = threadIdx.x, lane = t & 63, wave = t >> 6;
  __shared__ float red[16];
  float m = -1e30f;
  for (int i = t; i < 8192; i += 1024) m = fmaxf(m, sc[i]);
  #pragma unroll
  for (int off = 32; off > 0; off >>= 1) m = fmaxf(m, __shfl_down(m, off, 64));
  if (lane == 0) red[wave] = m;
  __syncthreads();
  if (t == 0){
    float mm = red[0];
    for (int w = 1; w < 16; ++w) mm = fmaxf(mm, red[w]);
    red[0] = mm;
  }
  __syncthreads();
  const float bmax = red[0];
  __syncthreads();
  float s = 0.f;
  for (int i = t; i < 8192; i += 1024) s += __expf(sc[i] - bmax);
  #pragma unroll
  for (int off = 32; off > 0; off >>= 1) s += __shfl_down(s, off, 64);
  if (lane == 0) red[wave] = s;
  __syncthreads();
  if (t == 0){
    float ss = 0.f;
    for (int w = 0; w < 16; ++w) ss += red[w];
    sred[0] = bmax; sred[1] = ss;
  }
}

__global__ __launch_bounds__(256) void weighted_part(
    const float* __restrict__ sc, const float* __restrict__ sred,
    const float* __restrict__ Z, float* __restrict__ part){
  const int blk = blockIdx.x, t = threadIdx.x;
  const int o = t & 127, h = t >> 7;
  const float bmax = sred[0], inv = 1.f / sred[1];
  float acc = 0.f;
  const int i0 = blk * 128;
  for (int i = i0 + h; i < i0 + 128; i += 2){
    float w = __expf(sc[i] - bmax) * inv;
    acc += w * Z[(size_t)i * 128 + o];
  }
  __shared__ float l[256];
  l[t] = acc;
  __syncthreads();
  if (h == 0) part[blk * 128 + o] = l[o] + l[o + 128];
}

__global__ __launch_bounds__(128) void final_red(
    const float* __restrict__ part, float* __restrict__ out){
  const int o = threadIdx.x;
  float s = 0.f;
  for (int b = 0; b < 64; ++b) s += part[b * 128 + o];
  out[o] = s;
}

// ---------------------------------------------------------------------------
extern "C" void kernel_launch(void* const* d_in, const int* in_sizes, int n_in,
                              void* d_out, int out_size, void* d_ws, size_t ws_size,
                              hipStream_t stream){
  const float* x  = (const float*)d_in[0];
  const float* A  = (const float*)d_in[1];
  const float* W1 = (const float*)d_in[2];
  const float* W2 = (const float*)d_in[3];
  const float* W3 = (const float*)d_in[4];
  const float* Wl = (const float*)d_in[5];
  const float* bl = (const float*)d_in[6];
  const float* q  = (const float*)d_in[7];
  const float* b  = (const float*)d_in[8];
  float* out = (float*)d_out;
  char* ws = (char*)d_ws;

  u16*   AB   = (u16*)(ws);                      // 128 MiB, tiled
  float* DS   = (float*)(ws + 134217728);        // 32 KiB
  u16*   VT   = (u16*)(ws + 134250496);          // 4 MiB, tiled
  u16*   HB   = (u16*)(ws + 138444800);          // 4 MiB [8192][256] row-major
  float* SC   = (float*)(ws + 142639104);        // 8192 f32 scores
  float* SP   = (float*)(ws + 142671872);        // 64*128 f32
  float* SRED = (float*)(ws + 142704640);        // {max, sumexp}

  rowsum_tileA<<<256, 1024, 0, stream>>>(A, AB, DS);
  // layer 1
  small_gemm<128, 256, false><<<512, 256, 0, stream>>>(x, W1, DS, VT);
  gemm_tlp<256, true, false><<<1024, 512, 0, stream>>>(AB, VT, DS, HB, nullptr);
  // layer 2
  small_gemm<256, 256, true><<<512, 256, 0, stream>>>(HB, W2, DS, VT);
  gemm_tlp<256, true, false><<<1024, 512, 0, stream>>>(AB, VT, DS, HB, nullptr);
  // layer 3 -> z_context f32 straight into d_out
  small_gemm<256, 128, true><<<256, 256, 0, stream>>>(HB, W3, DS, VT);
  gemm_tlp<128, false, true><<<512, 512, 0, stream>>>(AB, VT, DS, nullptr, out);
  // attention pooling
  attn_scores<<<512, 256, 0, stream>>>(out, Wl, bl, q, b, SC);
  softmax_red<<<1, 1024, 0, stream>>>(SC, SRED);
  weighted_part<<<64, 256, 0, stream>>>(SC, SRED, out, SP);
  final_red<<<1, 128, 0, stream>>>(SP, out + 8192 * 128);
}

// Round 11
// 377.017 us; speedup vs baseline: 1.2600x; 1.2600x over previous
//
#include <hip/hip_runtime.h>

typedef unsigned short u16;
typedef unsigned int   u32;
typedef __bf16 bf16x8 __attribute__((ext_vector_type(8)));
typedef float  f32x4  __attribute__((ext_vector_type(4)));
typedef float  f32x16 __attribute__((ext_vector_type(16)));

__device__ __forceinline__ u16 f2bf(float f){
  u32 u = __float_as_uint(f);
  u32 r = (u + 0x7FFFu + ((u >> 16) & 1u)) >> 16;   // RNE
  return (u16)r;
}

// Inline-asm load (survives hipcc's load-sinking). "=&v": dest must not
// alias the address pair (delayed write).
#define GLD(dst, p, OFF) \
  asm volatile("global_load_dwordx4 %0, %1, off offset:" OFF \
               : "=&v"(dst) : "v"(p))
#define WAITV(N) do { \
    asm volatile("s_waitcnt vmcnt(" N ")"); \
    __builtin_amdgcn_sched_barrier(0); \
  } while (0)

// ===========================================================================
// TILED OPERAND LAYOUT (validated R8: 735->397us):
// tile = 32 rows x 16 k = 1KB; elem (row,k) -> tile (row>>5, k>>4),
// lane = (row&31)|(((k>>3)&1)<<5), byte = tile*1024 + lane*16 + (k&7)*2.
// A consumer load of one tile = ONE contiguous 1KB block in exact lane order
// -> also the perfect global_load_lds source (linear dest, no swizzle).
//
// R9 (less L2 traffic: null) + R10 (2x TLP: regression, A cross-XCD dup)
// falsified L2-BW and latency. Surviving binder: per-WAVE operand
// duplication / per-CU VMEM work. R11: LDS-staged F=256 GEMM (m97
// structure) -> each operand byte enters the CU exactly once.
// ===========================================================================

// ---------------------------------------------------------------------------
// Pass 1: row sums + f32->bf16 + transpose to tiled layout via LDS.
// ---------------------------------------------------------------------------
__global__ __launch_bounds__(1024) void rowsum_tileA(
    const float* __restrict__ A, u16* __restrict__ Ab, float* __restrict__ ds){
  __shared__ u16 lt[8192];               // 16 tiles x 512 u16 = 16 KB
  const int t = threadIdx.x;
  const int r = t >> 5, q = t & 31;      // row 0..31, 32 threads/row
  const int rg = blockIdx.x;
  const float* ar = A + ((size_t)rg * 32 + r) * 8192;
  float s = 0.f;
  for (int ch = 0; ch < 32; ++ch){
    #pragma unroll
    for (int j = 0; j < 2; ++j){
      const int c4 = ch * 64 + j * 32 + q;           // float4 col index
      float4 v = ((const float4*)ar)[c4];
      s += (v.x + v.y) + (v.z + v.w);
      const int cl = (j * 32 + q) * 4;               // local col 0..255
      const int idx = (cl >> 4) * 512 + ((r | (((cl >> 3) & 1) << 5)) * 8) + (cl & 7);
      ushort4 o;
      o.x = f2bf(v.x); o.y = f2bf(v.y); o.z = f2bf(v.z); o.w = f2bf(v.w);
      *(ushort4*)(lt + idx) = o;
    }
    __syncthreads();
    uint4* dst = (uint4*)(Ab + ((size_t)rg * 512 + ch * 16) * 512);
    dst[t] = ((const uint4*)lt)[t];                  // linear 16KB, coalesced
    __syncthreads();
  }
  #pragma unroll
  for (int m = 16; m > 0; m >>= 1) s += __shfl_xor(s, m, 64);
  if (q == 0) ds[rg * 32 + r] = rsqrtf(s);
}

// ---------------------------------------------------------------------------
// Small feature GEMM: Vt tiles = bf16( ds[i] * sum_k in[i][k] * W[k][o] )
// Output in tiled layout.
// ---------------------------------------------------------------------------
template<int K, int F, bool INBF16>
__global__ __launch_bounds__(256) void small_gemm(
    const void* __restrict__ inp, const float* __restrict__ W,
    const float* __restrict__ ds, u16* __restrict__ Vt){
  constexpr int G   = 256 / F;     // 1 (F=256) or 2 (F=128)
  constexpr int RPB = 16 * G;      // rows per block
  __shared__ float xs[RPB * K];
  const int t  = threadIdx.x;
  const int r0 = blockIdx.x * RPB;
  if constexpr (INBF16){
    const u16* ip = (const u16*)inp + (size_t)r0 * K;
    constexpr int IT = (RPB * K) / (256 * 8);
    #pragma unroll
    for (int j = 0; j < IT; ++j){
      int c = j * 256 + t;
      uint4 v = ((const uint4*)ip)[c];
      float* xp = xs + c * 8;
      xp[0] = __uint_as_float((v.x & 0xFFFFu) << 16);
      xp[1] = __uint_as_float(v.x & 0xFFFF0000u);
      xp[2] = __uint_as_float((v.y & 0xFFFFu) << 16);
      xp[3] = __uint_as_float(v.y & 0xFFFF0000u);
      xp[4] = __uint_as_float((v.z & 0xFFFFu) << 16);
      xp[5] = __uint_as_float(v.z & 0xFFFF0000u);
      xp[6] = __uint_as_float((v.w & 0xFFFFu) << 16);
      xp[7] = __uint_as_float(v.w & 0xFFFF0000u);
    }
  } else {
    const float* ip = (const float*)inp + (size_t)r0 * K;
    constexpr int IT = (RPB * K) / (256 * 4);
    #pragma unroll
    for (int j = 0; j < IT; ++j){
      int c = j * 256 + t;
      ((float4*)xs)[c] = ((const float4*)ip)[c];
    }
  }
  __syncthreads();
  const int o = t % F, g = t / F;
  float acc[16];
  #pragma unroll
  for (int r = 0; r < 16; ++r) acc[r] = 0.f;
  const float* xr = xs + g * 16 * K;
  for (int k = 0; k < K; k += 4){
    float w0 = W[(k+0)*F + o];
    float w1 = W[(k+1)*F + o];
    float w2 = W[(k+2)*F + o];
    float w3 = W[(k+3)*F + o];
    #pragma unroll
    for (int r = 0; r < 16; ++r){
      float4 xv = *(const float4*)(xr + r*K + k);
      acc[r] += xv.x*w0 + xv.y*w1 + xv.z*w2 + xv.w*w3;
    }
  }
  const int rb = r0 + g * 16;              // 16-aligned -> one k-tile
  union { u16 u[16]; uint4 v[2]; } pk;
  #pragma unroll
  for (int r = 0; r < 16; ++r) pk.u[r] = f2bf(acc[r] * ds[rb + r]);
  const size_t tile = ((size_t)(o >> 5) * 512 + (rb >> 4)) * 512;
  uint4* dst = (uint4*)(Vt + tile + (size_t)(o & 31) * 8);
  dst[0]  = pk.v[0];
  dst[32] = pk.v[1];
}

// ---------------------------------------------------------------------------
// F=256 big GEMM, LDS-staged (m97 structure on tiled operands):
// 512 blocks x 256 thr; block = 64 rows x 64 cols, full K=8192.
// rowg = bid&127 (FAST: the 4 A-sharing blocks land on the SAME XCD),
// colg = bid>>7. 4 waves = 2x2 of 32x32. BK=128 (8 k-tiles), double-buffered
// global_load_lds (width 16), ONE barrier per chunk, 64 chunks.
// Per-CU staged bytes: 2 blocks x 2MB, zero duplication.
// H = relu(ds * (Ab @ Vt^T)) in bf16.
// ---------------------------------------------------------------------------
__global__ __launch_bounds__(256) void gemm_lds256(
    const u16* __restrict__ Ab, const u16* __restrict__ Vt,
    const float* __restrict__ ds, u16* __restrict__ Hout){
  __shared__ u16 As[2][32 * 512];        // 2 x 32KB (32 tiles of 1KB each)
  const int t = threadIdx.x, w = t >> 6, lane = t & 63;
  const int wr = w >> 1, wc = w & 1;
  const int rowg = blockIdx.x & 127;
  const int colg = blockIdx.x >> 7;      // 0..3

  // wave w stages k-tiles kt = w and w+4 of each of the 4 panels.
  // Slots: A rt0 -> kt, A rt1 -> 8+kt, B ct0 -> 16+kt, B ct1 -> 24+kt.
  const u16* sA0 = Ab + ((size_t)(rowg * 2 + 0) * 512 + w) * 512 + lane * 8;
  const u16* sA1 = Ab + ((size_t)(rowg * 2 + 1) * 512 + w) * 512 + lane * 8;
  const u16* sB0 = Vt + ((size_t)(colg * 2 + 0) * 512 + w) * 512 + lane * 8;
  const u16* sB1 = Vt + ((size_t)(colg * 2 + 1) * 512 + w) * 512 + lane * 8;

  f32x16 acc;
  #pragma unroll
  for (int i = 0; i < 16; ++i) acc[i] = 0.f;

  auto stage = [&](int buf, int c){
    u16* L = &As[buf][0];
    #pragma unroll
    for (int h = 0; h < 2; ++h){                 // kt = w + 4h
      const size_t so = (size_t)c * 4096 + (size_t)h * 4 * 512;
      const int ko = w + h * 4;
      __builtin_amdgcn_global_load_lds(
        (const __attribute__((address_space(1))) u32*)(sA0 + so),
        (__attribute__((address_space(3))) u32*)(L + (0 + ko) * 512 + lane * 8), 16, 0, 0);
      __builtin_amdgcn_global_load_lds(
        (const __attribute__((address_space(1))) u32*)(sA1 + so),
        (__attribute__((address_space(3))) u32*)(L + (8 + ko) * 512 + lane * 8), 16, 0, 0);
      __builtin_amdgcn_global_load_lds(
        (const __attribute__((address_space(1))) u32*)(sB0 + so),
        (__attribute__((address_space(3))) u32*)(L + (16 + ko) * 512 + lane * 8), 16, 0, 0);
      __builtin_amdgcn_global_load_lds(
        (const __attribute__((address_space(1))) u32*)(sB1 + so),
        (__attribute__((address_space(3))) u32*)(L + (24 + ko) * 512 + lane * 8), 16, 0, 0);
    }
  };
  auto compute = [&](int buf){
    const u16* lA = &As[buf][(wr * 8) * 512];
    const u16* lB = &As[buf][(16 + wc * 8) * 512];
    #pragma unroll
    for (int kt = 0; kt < 8; ++kt){
      bf16x8 a = *(const bf16x8*)(const void*)(lA + kt * 512 + lane * 8);
      bf16x8 b = *(const bf16x8*)(const void*)(lB + kt * 512 + lane * 8);
      acc = __builtin_amdgcn_mfma_f32_32x32x16_bf16(a, b, acc, 0, 0, 0);
    }
  };

  stage(0, 0);
  __syncthreads();
  for (int c = 0; c < 64; ++c){
    if (c < 63) stage((c + 1) & 1, c + 1);
    compute(c & 1);
    __syncthreads();
  }

  // epilogue (C/D layout m74/m101): col = lane&31, row = (r&3)+8*(r>>2)+4*(lane>>5)
  const int rhi = (lane >> 5) << 2;
  const int cl  = lane & 31;
  const int rbase = rowg * 64 + wr * 32;
  const int cbase = colg * 64 + wc * 32;
  #pragma unroll
  for (int r = 0; r < 16; ++r){
    const int rl = (r & 3) + ((r >> 2) << 3) + rhi;
    const int row = rbase + rl;
    float v = acc[r] * ds[row];
    v = fmaxf(v, 0.f);
    Hout[(size_t)row * 256 + cbase + cl] = f2bf(v);
  }
}

// ---------------------------------------------------------------------------
// F=128 big GEMM (R8-proven register-direct pipeline, kept as control):
// 256 blocks x 1024 thr = 16 waves = 4 ks x 4 cg; CT=1; counted vmcnt.
// ---------------------------------------------------------------------------
template<int F, bool RELU, bool OUTF32>
__global__ __launch_bounds__(1024, 4) void gemm_pipe(
    const u16* __restrict__ Ab, const u16* __restrict__ Vt,
    const float* __restrict__ ds, u16* __restrict__ Hout, float* __restrict__ Fout){
  constexpr int CT  = F / 128;          // 1 for F=128
  __shared__ float red[2][32][F];

  const int t = threadIdx.x, wave = t >> 6, lane = t & 63;
  const int ks = wave >> 2;
  const int cg = wave & 3;
  const int row0 = blockIdx.x * 32;
  const int colb = cg * (F / 4);

  const u16* pa = Ab + ((size_t)blockIdx.x * 512 + ks * 128) * 512 + lane * 8;

  f32x16 acc0;
  #pragma unroll
  for (int i = 0; i < 16; ++i) acc0[i] = 0.f;

  const u16* pb0 = Vt + ((size_t)cg * 512 + ks * 128) * 512 + lane * 8;
  bf16x8 aQ[4], b0Q[4];
  GLD(aQ[0],pa,"0");    GLD(b0Q[0],pb0,"0");
  GLD(aQ[1],pa,"1024"); GLD(b0Q[1],pb0,"1024");
  GLD(aQ[2],pa,"2048"); GLD(b0Q[2],pb0,"2048");
  GLD(aQ[3],pa,"3072"); GLD(b0Q[3],pb0,"3072");
  pa += 2048; pb0 += 2048;
  #define STEP1(U, OFF) \
    WAITV("6"); \
    acc0 = __builtin_amdgcn_mfma_f32_32x32x16_bf16(aQ[U], b0Q[U], acc0, 0, 0, 0); \
    GLD(aQ[U],pa,OFF); GLD(b0Q[U],pb0,OFF)
  for (int it = 0; it < 31; ++it){
    STEP1(0, "0");
    STEP1(1, "1024");
    STEP1(2, "2048");
    STEP1(3, "3072");
    pa += 2048; pb0 += 2048;
  }
  #undef STEP1
  WAITV("6");
  acc0 = __builtin_amdgcn_mfma_f32_32x32x16_bf16(aQ[0], b0Q[0], acc0, 0, 0, 0);
  WAITV("4");
  acc0 = __builtin_amdgcn_mfma_f32_32x32x16_bf16(aQ[1], b0Q[1], acc0, 0, 0, 0);
  WAITV("2");
  acc0 = __builtin_amdgcn_mfma_f32_32x32x16_bf16(aQ[2], b0Q[2], acc0, 0, 0, 0);
  WAITV("0");
  acc0 = __builtin_amdgcn_mfma_f32_32x32x16_bf16(aQ[3], b0Q[3], acc0, 0, 0, 0);

  const int rhi = (lane >> 5) << 2;
  const int cl  = lane & 31;
  if (ks >= 2){
    #pragma unroll
    for (int r = 0; r < 16; ++r)
      red[ks - 2][(r & 3) + ((r >> 2) << 3) + rhi][colb + cl] = acc0[r];
  }
  __syncthreads();
  if (ks < 2){
    #pragma unroll
    for (int r = 0; r < 16; ++r)
      acc0[r] += red[ks][(r & 3) + ((r >> 2) << 3) + rhi][colb + cl];
  }
  __syncthreads();
  if (ks == 1){
    #pragma unroll
    for (int r = 0; r < 16; ++r)
      red[0][(r & 3) + ((r >> 2) << 3) + rhi][colb + cl] = acc0[r];
  }
  __syncthreads();
  if (ks == 0){
    #pragma unroll
    for (int r = 0; r < 16; ++r){
      const int rl = (r & 3) + ((r >> 2) << 3) + rhi;
      float v = acc0[r] + red[0][rl][colb + cl];
      const int row = row0 + rl;
      v *= ds[row];
      if (RELU) v = fmaxf(v, 0.f);
      if (OUTF32) Fout[(size_t)row * F + colb + cl] = v;
      else        Hout[(size_t)row * F + colb + cl] = f2bf(v);
    }
  }
}

// ---------------------------------------------------------------------------
// Attention scores: sc[i] = tanh(Z[i,:] @ Wl^T + bl) @ q + b
// ---------------------------------------------------------------------------
__device__ __forceinline__ float tanh_fast(float x){
  x = fminf(fmaxf(x, -15.f), 15.f);
  float e = __expf(2.f * x);
  return (e - 1.f) / (e + 1.f);
}

__global__ __launch_bounds__(256) void attn_scores(
    const float* __restrict__ Z, const float* __restrict__ Wl,
    const float* __restrict__ bl, const float* __restrict__ q,
    const float* __restrict__ bsc, float* __restrict__ sc){
  __shared__ float wl[128 * 128];          // 64 KiB exactly, swizzled
  const int t = threadIdx.x, lane = t & 63, wave = t >> 6;
  for (int j = 0; j < 64; ++j){
    int idx = j * 256 + t;
    int o = idx >> 7, k = idx & 127;
    int c = k >> 2, e = k & 3;
    wl[o * 128 + (((c ^ (o & 31)) << 2) | e)] = Wl[idx];
  }
  __syncthreads();
  const float bl0 = bl[lane], bl1 = bl[lane + 64];
  const float q0  = q[lane],  q1  = q[lane + 64];
  const float bb  = bsc[0];
  const int r0 = blockIdx.x * 16;
  for (int rr = 0; rr < 4; ++rr){
    int r = r0 + wave * 4 + rr;
    float d0 = 0.f, d1 = 0.f;
    #pragma unroll
    for (int c = 0; c < 32; ++c){
      float4 zv = *(const float4*)(Z + (size_t)r * 128 + c * 4);
      float4 w0 = *(const float4*)&wl[ lane      * 128 + ((c ^ (lane & 31)) << 2)];
      float4 w1 = *(const float4*)&wl[(lane + 64)* 128 + ((c ^ (lane & 31)) << 2)];
      d0 += zv.x*w0.x + zv.y*w0.y + zv.z*w0.z + zv.w*w0.w;
      d1 += zv.x*w1.x + zv.y*w1.y + zv.z*w1.z + zv.w*w1.w;
    }
    float s = tanh_fast(d0 + bl0) * q0 + tanh_fast(d1 + bl1) * q1;
    #pragma unroll
    for (int off = 32; off > 0; off >>= 1) s += __shfl_down(s, off, 64);
    if (lane == 0) sc[r] = s + bb;
  }
}

__global__ __launch_bounds__(1024) void softmax_red(
    const float* __restrict__ sc, float* __restrict__ sred){
  const int t = threadIdx.x, lane = t & 63, wave = t >> 6;
  __shared__ float red[16];
  float m = -1e30f;
  for (int i = t; i < 8192; i += 1024) m = fmaxf(m, sc[i]);
  #pragma unroll
  for (int off = 32; off > 0; off >>= 1) m = fmaxf(m, __shfl_down(m, off, 64));
  if (lane == 0) red[wave] = m;
  __syncthreads();
  if (t == 0){
    float mm = red[0];
    for (int w = 1; w < 16; ++w) mm = fmaxf(mm, red[w]);
    red[0] = mm;
  }
  __syncthreads();
  const float bmax = red[0];
  __syncthreads();
  float s = 0.f;
  for (int i = t; i < 8192; i += 1024) s += __expf(sc[i] - bmax);
  #pragma unroll
  for (int off = 32; off > 0; off >>= 1) s += __shfl_down(s, off, 64);
  if (lane == 0) red[wave] = s;
  __syncthreads();
  if (t == 0){
    float ss = 0.f;
    for (int w = 0; w < 16; ++w) ss += red[w];
    sred[0] = bmax; sred[1] = ss;
  }
}

__global__ __launch_bounds__(256) void weighted_part(
    const float* __restrict__ sc, const float* __restrict__ sred,
    const float* __restrict__ Z, float* __restrict__ part){
  const int blk = blockIdx.x, t = threadIdx.x;
  const int o = t & 127, h = t >> 7;
  const float bmax = sred[0], inv = 1.f / sred[1];
  float acc = 0.f;
  const int i0 = blk * 128;
  for (int i = i0 + h; i < i0 + 128; i += 2){
    float w = __expf(sc[i] - bmax) * inv;
    acc += w * Z[(size_t)i * 128 + o];
  }
  __shared__ float l[256];
  l[t] = acc;
  __syncthreads();
  if (h == 0) part[blk * 128 + o] = l[o] + l[o + 128];
}

__global__ __launch_bounds__(128) void final_red(
    const float* __restrict__ part, float* __restrict__ out){
  const int o = threadIdx.x;
  float s = 0.f;
  for (int b = 0; b < 64; ++b) s += part[b * 128 + o];
  out[o] = s;
}

// ---------------------------------------------------------------------------
extern "C" void kernel_launch(void* const* d_in, const int* in_sizes, int n_in,
                              void* d_out, int out_size, void* d_ws, size_t ws_size,
                              hipStream_t stream){
  const float* x  = (const float*)d_in[0];
  const float* A  = (const float*)d_in[1];
  const float* W1 = (const float*)d_in[2];
  const float* W2 = (const float*)d_in[3];
  const float* W3 = (const float*)d_in[4];
  const float* Wl = (const float*)d_in[5];
  const float* bl = (const float*)d_in[6];
  const float* q  = (const float*)d_in[7];
  const float* b  = (const float*)d_in[8];
  float* out = (float*)d_out;
  char* ws = (char*)d_ws;

  u16*   AB   = (u16*)(ws);                      // 128 MiB, tiled
  float* DS   = (float*)(ws + 134217728);        // 32 KiB
  u16*   VT   = (u16*)(ws + 134250496);          // 4 MiB, tiled
  u16*   HB   = (u16*)(ws + 138444800);          // 4 MiB [8192][256] row-major
  float* SC   = (float*)(ws + 142639104);        // 8192 f32 scores
  float* SP   = (float*)(ws + 142671872);        // 64*128 f32
  float* SRED = (float*)(ws + 142704640);        // {max, sumexp}

  rowsum_tileA<<<256, 1024, 0, stream>>>(A, AB, DS);
  // layer 1
  small_gemm<128, 256, false><<<512, 256, 0, stream>>>(x, W1, DS, VT);
  gemm_lds256<<<512, 256, 0, stream>>>(AB, VT, DS, HB);
  // layer 2
  small_gemm<256, 256, true><<<512, 256, 0, stream>>>(HB, W2, DS, VT);
  gemm_lds256<<<512, 256, 0, stream>>>(AB, VT, DS, HB);
  // layer 3 -> z_context f32 straight into d_out
  small_gemm<256, 128, true><<<256, 256, 0, stream>>>(HB, W3, DS, VT);
  gemm_pipe<128, false, true><<<256, 1024, 0, stream>>>(AB, VT, DS, nullptr, out);
  // attention pooling
  attn_scores<<<512, 256, 0, stream>>>(out, Wl, bl, q, b, SC);
  softmax_red<<<1, 1024, 0, stream>>>(SC, SRED);
  weighted_part<<<64, 256, 0, stream>>>(SC, SRED, out, SP);
  final_red<<<1, 128, 0, stream>>>(SP, out + 8192 * 128);
}